// Round 1
// baseline (1594.663 us; speedup 1.0000x reference)
//
#include <hip/hip_runtime.h>

#define DMDL 3072
#define SEQ  2560
#define STXT 512
#define HEADS 24
#define DHD  128

typedef float f32x4 __attribute__((ext_vector_type(4)));
typedef __bf16 bf16x8 __attribute__((ext_vector_type(8)));
typedef unsigned short u16x4 __attribute__((ext_vector_type(4)));

static __device__ __forceinline__ unsigned short f2bf(float f) {
  unsigned u = __float_as_uint(f);
  u += 0x7fffu + ((u >> 16) & 1u);
  return (unsigned short)(u >> 16);
}
static __device__ __forceinline__ float bf2f(unsigned short u) {
  return __uint_as_float(((unsigned)u) << 16);
}

// ---------------------------------------------------------------------------
// GEMM: C[M][N] = A[M][K] @ Bw[N][K]^T + bias[N]   (all f32 in/out, bf16 MFMA)
// 128x128 tile, BK=32, 256 threads (4 waves, 2x2 of 64x64), f32->bf16 staging.
// M,N multiples of 128; K multiple of 32.
// ---------------------------------------------------------------------------
__global__ __launch_bounds__(256) void gemm_bias_kernel(
    const float* __restrict__ A, const float* __restrict__ Bw,
    const float* __restrict__ bias, float* __restrict__ C,
    int M, int N, int K) {
  __shared__ unsigned short Al[128][32];
  __shared__ unsigned short Bl[128][32];
  const int t = threadIdx.x;
  const int w = t >> 6, l = t & 63;
  const int row0 = blockIdx.y << 7, col0 = blockIdx.x << 7;
  const int wr = (w >> 1) << 6, wc = (w & 1) << 6;
  const int l15 = l & 15, lg = l >> 4;
  f32x4 acc[4][4];
#pragma unroll
  for (int i = 0; i < 4; i++)
#pragma unroll
    for (int j = 0; j < 4; j++) acc[i][j] = (f32x4){0.f, 0.f, 0.f, 0.f};

  for (int k0 = 0; k0 < K; k0 += 32) {
    float4 av[4], bv[4];
#pragma unroll
    for (int p = 0; p < 4; p++) {
      int idx = (p << 8) + t;
      int r = idx >> 3, c = (idx & 7) << 2;
      av[p] = *(const float4*)(A + (size_t)(row0 + r) * K + k0 + c);
      bv[p] = *(const float4*)(Bw + (size_t)(col0 + r) * K + k0 + c);
    }
    __syncthreads();
#pragma unroll
    for (int p = 0; p < 4; p++) {
      int idx = (p << 8) + t;
      int r = idx >> 3, c = (idx & 7) << 2;
      u16x4 a4 = { f2bf(av[p].x), f2bf(av[p].y), f2bf(av[p].z), f2bf(av[p].w) };
      u16x4 b4 = { f2bf(bv[p].x), f2bf(bv[p].y), f2bf(bv[p].z), f2bf(bv[p].w) };
      *(u16x4*)&Al[r][c] = a4;
      *(u16x4*)&Bl[r][c] = b4;
    }
    __syncthreads();
    bf16x8 af[4], bfr[4];
#pragma unroll
    for (int i = 0; i < 4; i++) {
      af[i]  = *(const bf16x8*)&Al[wr + (i << 4) + l15][lg << 3];
      bfr[i] = *(const bf16x8*)&Bl[wc + (i << 4) + l15][lg << 3];
    }
#pragma unroll
    for (int i = 0; i < 4; i++)
#pragma unroll
      for (int j = 0; j < 4; j++)
        acc[i][j] = __builtin_amdgcn_mfma_f32_16x16x32_bf16(af[i], bfr[j], acc[i][j], 0, 0, 0);
  }
#pragma unroll
  for (int i = 0; i < 4; i++)
#pragma unroll
    for (int j = 0; j < 4; j++) {
      int col = col0 + wc + (j << 4) + l15;
      float bb = bias[col];
      int rbase = row0 + wr + (i << 4) + (lg << 2);
#pragma unroll
      for (int r2 = 0; r2 < 4; r2++)
        C[(size_t)(rbase + r2) * N + col] = acc[i][j][r2] + bb;
    }
}

// ---------------------------------------------------------------------------
// LoRA down: tmp[M][16] = X[M][3072] @ down[16][3072]^T   (one block per row)
// ---------------------------------------------------------------------------
__global__ __launch_bounds__(256) void lora_down_kernel(
    const float* __restrict__ X, const float* __restrict__ dwn,
    float* __restrict__ tmp) {
  const int t = threadIdx.x, w = t >> 6, l = t & 63;
  const int m = blockIdx.x;
  const float* x = X + (size_t)m * DMDL;
  float acc[16];
#pragma unroll
  for (int r = 0; r < 16; r++) acc[r] = 0.f;
  for (int k = t; k < DMDL; k += 256) {
    float xv = x[k];
#pragma unroll
    for (int r = 0; r < 16; r++) acc[r] += xv * dwn[r * DMDL + k];
  }
#pragma unroll
  for (int off = 1; off < 64; off <<= 1)
#pragma unroll
    for (int r = 0; r < 16; r++) acc[r] += __shfl_xor(acc[r], off);
  __shared__ float red[4][16];
  if (l == 0)
#pragma unroll
    for (int r = 0; r < 16; r++) red[w][r] = acc[r];
  __syncthreads();
  if (t < 16) tmp[(size_t)m * 16 + t] = red[0][t] + red[1][t] + red[2][t] + red[3][t];
}

// LoRA up + add: X[M][3072] += tmp[M][16] @ up[3072][16]^T
__global__ __launch_bounds__(256) void lora_up_kernel(
    float* __restrict__ X, const float* __restrict__ tmp,
    const float* __restrict__ up) {
  const int idx = blockIdx.x * 256 + threadIdx.x;  // M*3072 threads
  const int m = idx / DMDL, n = idx - m * DMDL;
  const float* tv = tmp + (size_t)m * 16;
  const float* uv = up + (size_t)n * 16;
  float s = 0.f;
#pragma unroll
  for (int r = 0; r < 16; r++) s += tv[r] * uv[r];
  X[idx] += s;
}

// ---------------------------------------------------------------------------
// Pack: RMSNorm(per-head) + RoPE + (q-scale) + f32->bf16, into [H][SEQ][DHD]
// grid (SEQ/4, HEADS, 3), block 256; wave per (s). z: 0=q 1=k 2=v
// ---------------------------------------------------------------------------
__global__ __launch_bounds__(256) void pack_kernel(
    const float* __restrict__ q0, const float* __restrict__ k0, const float* __restrict__ v0,
    const float* __restrict__ eq, const float* __restrict__ ek, const float* __restrict__ ev,
    const float* __restrict__ nq, const float* __restrict__ nk,
    const float* __restrict__ naq, const float* __restrict__ nak,
    const float* __restrict__ rc, const float* __restrict__ rsn,
    unsigned short* __restrict__ Qp, unsigned short* __restrict__ Kp,
    unsigned short* __restrict__ Vp) {
  const int t = threadIdx.x, w = t >> 6, l = t & 63;
  const int s = blockIdx.x * 4 + w;
  const int h = blockIdx.y;
  const int which = blockIdx.z;
  const float* src;
  const float* nw = nullptr;
  if (s < STXT) {
    const float* base = (which == 0) ? eq : (which == 1) ? ek : ev;
    src = base + (size_t)s * DMDL + h * DHD;
    if (which == 0) nw = naq; else if (which == 1) nw = nak;
  } else {
    const float* base = (which == 0) ? q0 : (which == 1) ? k0 : v0;
    src = base + (size_t)(s - STXT) * DMDL + h * DHD;
    if (which == 0) nw = nq; else if (which == 1) nw = nk;
  }
  float2 x = *(const float2*)(src + 2 * l);
  float y1, y2;
  if (which < 2) {
    float ss = x.x * x.x + x.y * x.y;
#pragma unroll
    for (int off = 1; off < 64; off <<= 1) ss += __shfl_xor(ss, off);
    float inv = rsqrtf(ss * (1.f / 128.f) + 1e-6f);
    float xw1 = x.x * inv * nw[2 * l];
    float xw2 = x.y * inv * nw[2 * l + 1];
    float c1 = rc[(size_t)s * DHD + 2 * l], c2 = rc[(size_t)s * DHD + 2 * l + 1];
    float s1 = rsn[(size_t)s * DHD + 2 * l], s2 = rsn[(size_t)s * DHD + 2 * l + 1];
    y1 = xw1 * c1 - xw2 * s1;
    y2 = xw2 * c2 + xw1 * s2;
    if (which == 0) { y1 *= 0.08838834764831845f; y2 *= 0.08838834764831845f; }
  } else {
    y1 = x.x; y2 = x.y;
  }
  unsigned short* dst = (which == 0) ? Qp : (which == 1) ? Kp : Vp;
  dst += ((size_t)h * SEQ + s) * DHD + 2 * l;
  unsigned pk = (unsigned)f2bf(y1) | ((unsigned)f2bf(y2) << 16);
  *(unsigned*)dst = pk;
}

// ---------------------------------------------------------------------------
// Flash attention. grid (SEQ/64, HEADS), block 256 (4 waves x 16 q-rows).
// KV tile = 64. Q pre-scaled by 1/sqrt(128). Out: attn[s][h*128+d] f32.
// ---------------------------------------------------------------------------
__global__ __launch_bounds__(256) void attn_kernel(
    const unsigned short* __restrict__ Qp, const unsigned short* __restrict__ Kp,
    const unsigned short* __restrict__ Vp, float* __restrict__ attnb) {
  __shared__ unsigned short Klds[64][128];
  __shared__ unsigned short Vt[128][64];
  __shared__ unsigned short Plds[4][16][64];
  const int t = threadIdx.x, w = t >> 6, l = t & 63;
  const int l15 = l & 15, lg = l >> 4;
  const int h = blockIdx.y;
  const int q0 = blockIdx.x * 64;
  const unsigned short* Qh = Qp + (size_t)h * SEQ * DHD;
  const unsigned short* Kh = Kp + (size_t)h * SEQ * DHD;
  const unsigned short* Vh = Vp + (size_t)h * SEQ * DHD;

  bf16x8 qf[4];
  {
    const unsigned short* qsrc = Qh + (size_t)(q0 + w * 16 + l15) * DHD + (lg << 3);
#pragma unroll
    for (int kf = 0; kf < 4; kf++) qf[kf] = *(const bf16x8*)(qsrc + kf * 32);
  }
  f32x4 o[8];
#pragma unroll
  for (int nc = 0; nc < 8; nc++) o[nc] = (f32x4){0.f, 0.f, 0.f, 0.f};
  float m[4] = {-1e30f, -1e30f, -1e30f, -1e30f};
  float sum[4] = {0.f, 0.f, 0.f, 0.f};

  for (int kv0 = 0; kv0 < SEQ; kv0 += 64) {
    __syncthreads();
    // stage K: 64x128 bf16 (row-major)
#pragma unroll
    for (int p = 0; p < 4; p++) {
      int f = (p << 8) + t;
      int r = f >> 4, c = (f & 15) << 3;
      *(uint4*)&Klds[r][c] = *(const uint4*)(Kh + (size_t)(kv0 + r) * DHD + c);
    }
    // stage V transposed: Vt[d][kv]
    {
      int r = t >> 2, d0 = (t & 3) << 5;
      const unsigned short* vsrc = Vh + (size_t)(kv0 + r) * DHD + d0;
#pragma unroll
      for (int b = 0; b < 4; b++) {
        uint4 vv = *(const uint4*)(vsrc + (b << 3));
        unsigned vals[4] = {vv.x, vv.y, vv.z, vv.w};
#pragma unroll
        for (int e = 0; e < 4; e++) {
          Vt[d0 + (b << 3) + 2 * e][r]     = (unsigned short)(vals[e] & 0xffffu);
          Vt[d0 + (b << 3) + 2 * e + 1][r] = (unsigned short)(vals[e] >> 16);
        }
      }
    }
    __syncthreads();
    // QK^T: sacc[c][row] for 4 chunks of 16 kv-cols
    f32x4 sacc[4];
#pragma unroll
    for (int c = 0; c < 4; c++) {
      sacc[c] = (f32x4){0.f, 0.f, 0.f, 0.f};
      const unsigned short* kbase = &Klds[c * 16 + l15][lg << 3];
#pragma unroll
      for (int kf = 0; kf < 4; kf++) {
        bf16x8 kb = *(const bf16x8*)(kbase + kf * 32);
        sacc[c] = __builtin_amdgcn_mfma_f32_16x16x32_bf16(qf[kf], kb, sacc[c], 0, 0, 0);
      }
    }
    // online softmax per q-row (rows = lg*4 + j)
    float sc4[4];
#pragma unroll
    for (int j = 0; j < 4; j++) {
      float mx = fmaxf(fmaxf(sacc[0][j], sacc[1][j]), fmaxf(sacc[2][j], sacc[3][j]));
#pragma unroll
      for (int off = 1; off < 16; off <<= 1) mx = fmaxf(mx, __shfl_xor(mx, off));
      float mnew = fmaxf(m[j], mx);
      float scale = exp2f((m[j] - mnew) * 1.44269504f);
      float pv[4];
      float ps = 0.f;
#pragma unroll
      for (int c = 0; c < 4; c++) {
        pv[c] = exp2f((sacc[c][j] - mnew) * 1.44269504f);
        ps += pv[c];
      }
#pragma unroll
      for (int off = 1; off < 16; off <<= 1) ps += __shfl_xor(ps, off);
      sum[j] = sum[j] * scale + ps;
      m[j] = mnew;
      sc4[j] = scale;
      int prow = (lg << 2) + j;
#pragma unroll
      for (int c = 0; c < 4; c++) Plds[w][prow][c * 16 + l15] = f2bf(pv[c]);
    }
#pragma unroll
    for (int nc = 0; nc < 8; nc++) {
      o[nc][0] *= sc4[0]; o[nc][1] *= sc4[1]; o[nc][2] *= sc4[2]; o[nc][3] *= sc4[3];
    }
    // PV: P(16x64) @ V(64x128)
#pragma unroll
    for (int kf2 = 0; kf2 < 2; kf2++) {
      bf16x8 pa = *(const bf16x8*)&Plds[w][l15][(lg << 3) + kf2 * 32];
#pragma unroll
      for (int nc = 0; nc < 8; nc++) {
        bf16x8 vb = *(const bf16x8*)&Vt[nc * 16 + l15][(lg << 3) + kf2 * 32];
        o[nc] = __builtin_amdgcn_mfma_f32_16x16x32_bf16(pa, vb, o[nc], 0, 0, 0);
      }
    }
  }
  // write out (normalize)
#pragma unroll
  for (int nc = 0; nc < 8; nc++)
#pragma unroll
    for (int j = 0; j < 4; j++) {
      int row = q0 + w * 16 + (lg << 2) + j;
      int col = h * DHD + nc * 16 + l15;
      attnb[(size_t)row * DMDL + col] = o[nc][j] / sum[j];
    }
}

// ---------------------------------------------------------------------------
// Bokeh LoRA down: tkv[2][4][16]
// ---------------------------------------------------------------------------
__global__ __launch_bounds__(256) void bokeh_down_kernel(
    const float* __restrict__ bok, const float* __restrict__ kbd,
    const float* __restrict__ vbd, float* __restrict__ tkv) {
  const int t = threadIdx.x, w = t >> 6, l = t & 63;
  const int mat = blockIdx.x >> 2, j = blockIdx.x & 3;
  const float* dwn = mat ? vbd : kbd;
  const float* x = bok + (size_t)j * DMDL;
  float acc[16];
#pragma unroll
  for (int r = 0; r < 16; r++) acc[r] = 0.f;
  for (int k = t; k < DMDL; k += 256) {
    float xv = x[k];
#pragma unroll
    for (int r = 0; r < 16; r++) acc[r] += xv * dwn[r * DMDL + k];
  }
#pragma unroll
  for (int off = 1; off < 64; off <<= 1)
#pragma unroll
    for (int r = 0; r < 16; r++) acc[r] += __shfl_xor(acc[r], off);
  __shared__ float red[4][16];
  if (l == 0)
#pragma unroll
    for (int r = 0; r < 16; r++) red[w][r] = acc[r];
  __syncthreads();
  if (t < 16) tkv[(mat * 4 + j) * 16 + t] = red[0][t] + red[1][t] + red[2][t] + red[3][t];
}

// Bokeh LoRA up: kdvd[8][3072] (0..3 = kd tokens, 4..7 = vd tokens)
__global__ __launch_bounds__(256) void bokeh_up_kernel(
    const float* __restrict__ tkv, const float* __restrict__ kbu,
    const float* __restrict__ vbu, float* __restrict__ kdvd) {
  const int idx = blockIdx.x * 256 + threadIdx.x;  // 24576
  const int mat = idx / 12288, rem = idx % 12288;
  const int j = rem / DMDL, n = rem % DMDL;
  const float* up = mat ? vbu : kbu;
  const float* tv = tkv + (mat * 4 + j) * 16;
  float s = 0.f;
#pragma unroll
  for (int r = 0; r < 16; r++) s += tv[r] * up[(size_t)n * 16 + r];
  kdvd[(size_t)(mat * 4 + j) * DMDL + n] = s;
}

// ---------------------------------------------------------------------------
// Bokeh cross-attn (4 keys): attn[s][h*128+d] += softmax(q.kd)@vd
// grid SEQ*HEADS/4, block 256; one wave per (h,s). Q already scaled.
// ---------------------------------------------------------------------------
__global__ __launch_bounds__(256) void cam_kernel(
    const unsigned short* __restrict__ Qp, const float* __restrict__ kdvd,
    float* __restrict__ attnb) {
  const int t = threadIdx.x, w = t >> 6, l = t & 63;
  const int id = blockIdx.x * 4 + w;
  const int h = id / SEQ, s = id % SEQ;
  const unsigned short* q = Qp + ((size_t)h * SEQ + s) * DHD + 2 * l;
  unsigned qp = *(const unsigned*)q;
  float q1 = bf2f((unsigned short)(qp & 0xffffu));
  float q2 = bf2f((unsigned short)(qp >> 16));
  float p[4];
#pragma unroll
  for (int j = 0; j < 4; j++) {
    const float* kd = kdvd + (size_t)j * DMDL + h * DHD + 2 * l;
    float d = q1 * kd[0] + q2 * kd[1];
#pragma unroll
    for (int off = 1; off < 64; off <<= 1) d += __shfl_xor(d, off);
    p[j] = d;
  }
  float mx = fmaxf(fmaxf(p[0], p[1]), fmaxf(p[2], p[3]));
  float ps = 0.f;
#pragma unroll
  for (int j = 0; j < 4; j++) { p[j] = exp2f((p[j] - mx) * 1.44269504f); ps += p[j]; }
  float rinv = 1.f / ps;
  float o1 = 0.f, o2 = 0.f;
#pragma unroll
  for (int j = 0; j < 4; j++) {
    const float* vd = kdvd + (size_t)(4 + j) * DMDL + h * DHD + 2 * l;
    o1 += p[j] * vd[0];
    o2 += p[j] * vd[1];
  }
  float* dst = attnb + (size_t)s * DMDL + h * DHD + 2 * l;
  dst[0] += o1 * rinv;
  dst[1] += o2 * rinv;
}

// ---------------------------------------------------------------------------
extern "C" void kernel_launch(void* const* d_in, const int* in_sizes, int n_in,
                              void* d_out, int out_size, void* d_ws, size_t ws_size,
                              hipStream_t stream) {
  (void)in_sizes; (void)n_in; (void)out_size; (void)ws_size;
  const float* hs  = (const float*)d_in[0];
  const float* enc = (const float*)d_in[1];
  const float* bok = (const float*)d_in[2];
  const float* rc  = (const float*)d_in[3];
  const float* rsn = (const float*)d_in[4];
  const float* Wq  = (const float*)d_in[5];
  const float* Wk  = (const float*)d_in[6];
  const float* Wv  = (const float*)d_in[7];
  const float* Waq = (const float*)d_in[8];
  const float* Wak = (const float*)d_in[9];
  const float* Wav = (const float*)d_in[10];
  const float* Wo  = (const float*)d_in[11];
  const float* Wao = (const float*)d_in[12];
  const float* bq  = (const float*)d_in[13];
  const float* bk  = (const float*)d_in[14];
  const float* bv  = (const float*)d_in[15];
  const float* baq = (const float*)d_in[16];
  const float* bak = (const float*)d_in[17];
  const float* bav = (const float*)d_in[18];
  const float* bo  = (const float*)d_in[19];
  const float* bao = (const float*)d_in[20];
  const float* nq  = (const float*)d_in[21];
  const float* nk  = (const float*)d_in[22];
  const float* naq = (const float*)d_in[23];
  const float* nak = (const float*)d_in[24];
  const float* kbd = (const float*)d_in[25];
  const float* vbd = (const float*)d_in[26];
  const float* qad = (const float*)d_in[27];
  const float* kad = (const float*)d_in[28];
  const float* kbu = (const float*)d_in[29];
  const float* vbu = (const float*)d_in[30];
  const float* qau = (const float*)d_in[31];
  const float* kau = (const float*)d_in[32];

  char* ws = (char*)d_ws;
  float* q0   = (float*)(ws + 0);
  float* k0   = (float*)(ws + 25165824);
  float* v0   = (float*)(ws + 50331648);
  float* eq   = (float*)(ws + 75497472);
  float* ek   = (float*)(ws + 81788928);
  float* ev   = (float*)(ws + 88080384);
  float* tmpq = (float*)(ws + 94371840);
  float* tmpk = (float*)(ws + 94502912);
  float* tkv  = (float*)(ws + 94633984);
  float* kdvd = (float*)(ws + 94638080);
  unsigned short* Qp = (unsigned short*)(ws + 94736384);
  unsigned short* Kp = (unsigned short*)(ws + 110465024);
  unsigned short* Vp = (unsigned short*)(ws + 126193664);
  float* attnb = (float*)(ws + 141922304);

  float* out_img = (float*)d_out;                       // 2048*3072
  float* out_enc = (float*)d_out + (size_t)2048 * 3072; // 512*3072

  dim3 blk(256);
  dim3 gQKV(24, 16);   // N/128=24, M/128=16 (M=2048)
  dim3 gE(24, 4);      // M=512

  // Projections
  gemm_bias_kernel<<<gQKV, blk, 0, stream>>>(hs, Wq, bq, q0, 2048, DMDL, DMDL);
  gemm_bias_kernel<<<gQKV, blk, 0, stream>>>(hs, Wk, bk, k0, 2048, DMDL, DMDL);
  gemm_bias_kernel<<<gQKV, blk, 0, stream>>>(hs, Wv, bv, v0, 2048, DMDL, DMDL);
  gemm_bias_kernel<<<gE, blk, 0, stream>>>(enc, Waq, baq, eq, 512, DMDL, DMDL);
  gemm_bias_kernel<<<gE, blk, 0, stream>>>(enc, Wak, bak, ek, 512, DMDL, DMDL);
  gemm_bias_kernel<<<gE, blk, 0, stream>>>(enc, Wav, bav, ev, 512, DMDL, DMDL);

  // LoRA on q,k (image stream)
  lora_down_kernel<<<2048, blk, 0, stream>>>(q0, qad, tmpq);
  lora_down_kernel<<<2048, blk, 0, stream>>>(k0, kad, tmpk);
  lora_up_kernel<<<24576, blk, 0, stream>>>(q0, tmpq, qau);
  lora_up_kernel<<<24576, blk, 0, stream>>>(k0, tmpk, kau);

  // RMSNorm + RoPE + pack to bf16 [H][S][D]
  pack_kernel<<<dim3(SEQ / 4, HEADS, 3), blk, 0, stream>>>(
      q0, k0, v0, eq, ek, ev, nq, nk, naq, nak, rc, rsn, Qp, Kp, Vp);

  // Main attention
  attn_kernel<<<dim3(SEQ / 64, HEADS), blk, 0, stream>>>(Qp, Kp, Vp, attnb);

  // Bokeh branch
  bokeh_down_kernel<<<8, blk, 0, stream>>>(bok, kbd, vbd, tkv);
  bokeh_up_kernel<<<96, blk, 0, stream>>>(tkv, kbu, vbu, kdvd);
  cam_kernel<<<SEQ * HEADS / 4, blk, 0, stream>>>(Qp, kdvd, attnb);

  // Output projections
  gemm_bias_kernel<<<gQKV, blk, 0, stream>>>(attnb + (size_t)STXT * DMDL, Wo, bo,
                                             out_img, 2048, DMDL, DMDL);
  gemm_bias_kernel<<<gE, blk, 0, stream>>>(attnb, Wao, bao, out_enc, 512, DMDL, DMDL);
}

// Round 2
// 999.791 us; speedup vs baseline: 1.5950x; 1.5950x over previous
//
#include <hip/hip_runtime.h>

#define DMDL 3072
#define SEQ  2560
#define STXT 512
#define HEADS 24
#define DHD  128

typedef float f32x4 __attribute__((ext_vector_type(4)));
typedef __bf16 bf16x8 __attribute__((ext_vector_type(8)));
typedef unsigned short u16x4 __attribute__((ext_vector_type(4)));

static __device__ __forceinline__ unsigned short f2bf(float f) {
  unsigned u = __float_as_uint(f);
  u += 0x7fffu + ((u >> 16) & 1u);
  return (unsigned short)(u >> 16);
}
static __device__ __forceinline__ float bf2f(unsigned short u) {
  return __uint_as_float(((unsigned)u) << 16);
}

// async global->LDS, 16B per lane. lds ptr must be wave-uniform base; HW
// writes lane i at base + i*16. Global ptr is per-lane.
static __device__ __forceinline__ void gload16(const unsigned short* g, unsigned short* l) {
  __builtin_amdgcn_global_load_lds(
      (const __attribute__((address_space(1))) unsigned int*)g,
      (__attribute__((address_space(3))) unsigned int*)l, 16, 0, 0);
}

// ---------------------------------------------------------------------------
// f32 -> bf16 convert, n multiple of 1024, grid = n/1024
// ---------------------------------------------------------------------------
__global__ __launch_bounds__(256) void convf2b_kernel(
    const float* __restrict__ src, unsigned short* __restrict__ dst) {
  const int idx4 = blockIdx.x * 256 + threadIdx.x;
  float4 v = *(const float4*)(src + (size_t)idx4 * 4);
  u16x4 b = { f2bf(v.x), f2bf(v.y), f2bf(v.z), f2bf(v.w) };
  *(u16x4*)(dst + (size_t)idx4 * 4) = b;
}

// ---------------------------------------------------------------------------
// GEMM: C[M][N] = A[M][K] @ Bw[N][K]^T + bias[N].  A,Bw bf16, C f32.
// 128x128 tile, BK=64, 4 waves (2x2 of 64x64). global_load_lds staging with
// pre-swizzled global source (slot ^= row&7); swizzled conflict-free ds_read.
// grid = (M/128)*(N/128) (multiple of 8), 1-D with XCD swizzle.
// ---------------------------------------------------------------------------
__global__ __launch_bounds__(256) void gemm_bf16_kernel(
    const unsigned short* __restrict__ A, const unsigned short* __restrict__ Bw,
    const float* __restrict__ bias, float* __restrict__ C,
    int M, int N, int K) {
  __shared__ unsigned short Al[128][64];
  __shared__ unsigned short Bl[128][64];
  const int t = threadIdx.x, w = t >> 6, l = t & 63;
  const int nbx = N >> 7;
  const int nwg = (M >> 7) * nbx;
  const int cpx = nwg >> 3;
  const int sid = (blockIdx.x & 7) * cpx + (blockIdx.x >> 3);
  const int by = sid / nbx, bx = sid - by * nbx;
  const int row0 = by << 7, col0 = bx << 7;
  const int wr = (w >> 1) << 6, wc = (w & 1) << 6;
  const int l15 = l & 15, lg = l >> 4;
  f32x4 acc[4][4];
#pragma unroll
  for (int i = 0; i < 4; i++)
#pragma unroll
    for (int j = 0; j < 4; j++) acc[i][j] = (f32x4){0.f, 0.f, 0.f, 0.f};

  for (int k0 = 0; k0 < K; k0 += 64) {
    __syncthreads();
#pragma unroll
    for (int g = 0; g < 4; g++) {
      const int jb = ((w << 2) + g) << 6;   // wave-uniform base slot
      const int jl = jb + l;
      const int row = jl >> 3, sl = jl & 7;
      const int col = ((sl ^ (row & 7)) << 3);
      gload16(A  + (size_t)(row0 + row) * K + k0 + col, ((unsigned short*)Al) + (size_t)jb * 8);
      gload16(Bw + (size_t)(col0 + row) * K + k0 + col, ((unsigned short*)Bl) + (size_t)jb * 8);
    }
    asm volatile("s_waitcnt vmcnt(0)" ::: "memory");
    __syncthreads();
#pragma unroll
    for (int kf = 0; kf < 2; kf++) {
      bf16x8 af[4], bfr[4];
#pragma unroll
      for (int i = 0; i < 4; i++) {
        const int ra = wr + (i << 4) + l15;
        af[i]  = *(const bf16x8*)&Al[ra][(((kf << 2) + lg) ^ (ra & 7)) << 3];
        const int rb = wc + (i << 4) + l15;
        bfr[i] = *(const bf16x8*)&Bl[rb][(((kf << 2) + lg) ^ (rb & 7)) << 3];
      }
      __builtin_amdgcn_s_setprio(1);
#pragma unroll
      for (int i = 0; i < 4; i++)
#pragma unroll
        for (int j = 0; j < 4; j++)
          acc[i][j] = __builtin_amdgcn_mfma_f32_16x16x32_bf16(af[i], bfr[j], acc[i][j], 0, 0, 0);
      __builtin_amdgcn_s_setprio(0);
    }
  }
#pragma unroll
  for (int i = 0; i < 4; i++)
#pragma unroll
    for (int j = 0; j < 4; j++) {
      const int col = col0 + wc + (j << 4) + l15;
      const float bb = bias[col];
      const int rbase = row0 + wr + (i << 4) + (lg << 2);
#pragma unroll
      for (int r2 = 0; r2 < 4; r2++)
        C[(size_t)(rbase + r2) * N + col] = acc[i][j][r2] + bb;
    }
}

// ---------------------------------------------------------------------------
// LoRA down: tmp[M][16] = X[M][3072] @ down[16][3072]^T
// ---------------------------------------------------------------------------
__global__ __launch_bounds__(256) void lora_down_kernel(
    const float* __restrict__ X, const float* __restrict__ dwn,
    float* __restrict__ tmp) {
  const int t = threadIdx.x, w = t >> 6, l = t & 63;
  const int m = blockIdx.x;
  const float* x = X + (size_t)m * DMDL;
  float acc[16];
#pragma unroll
  for (int r = 0; r < 16; r++) acc[r] = 0.f;
  for (int k = t; k < DMDL; k += 256) {
    float xv = x[k];
#pragma unroll
    for (int r = 0; r < 16; r++) acc[r] += xv * dwn[r * DMDL + k];
  }
#pragma unroll
  for (int off = 1; off < 64; off <<= 1)
#pragma unroll
    for (int r = 0; r < 16; r++) acc[r] += __shfl_xor(acc[r], off);
  __shared__ float red[4][16];
  if (l == 0)
#pragma unroll
    for (int r = 0; r < 16; r++) red[w][r] = acc[r];
  __syncthreads();
  if (t < 16) tmp[(size_t)m * 16 + t] = red[0][t] + red[1][t] + red[2][t] + red[3][t];
}

__global__ __launch_bounds__(256) void lora_up_kernel(
    float* __restrict__ X, const float* __restrict__ tmp,
    const float* __restrict__ up) {
  const int idx = blockIdx.x * 256 + threadIdx.x;
  const int m = idx / DMDL, n = idx - m * DMDL;
  const float* tv = tmp + (size_t)m * 16;
  const float* uv = up + (size_t)n * 16;
  float s = 0.f;
#pragma unroll
  for (int r = 0; r < 16; r++) s += tv[r] * uv[r];
  X[idx] += s;
}

// ---------------------------------------------------------------------------
// Pack q,k: RMSNorm + RoPE + (q-scale) + bf16, into [H][SEQ][DHD]
// grid (SEQ/4, HEADS, 2), block 256; wave per s. z: 0=q 1=k
// ---------------------------------------------------------------------------
__global__ __launch_bounds__(256) void pack_kernel(
    const float* __restrict__ q0, const float* __restrict__ k0,
    const float* __restrict__ eq, const float* __restrict__ ek,
    const float* __restrict__ nq, const float* __restrict__ nk,
    const float* __restrict__ naq, const float* __restrict__ nak,
    const float* __restrict__ rc, const float* __restrict__ rsn,
    unsigned short* __restrict__ Qp, unsigned short* __restrict__ Kp) {
  const int t = threadIdx.x, w = t >> 6, l = t & 63;
  const int s = blockIdx.x * 4 + w;
  const int h = blockIdx.y;
  const int which = blockIdx.z;
  const float* src;
  const float* nw;
  if (s < STXT) {
    src = ((which == 0) ? eq : ek) + (size_t)s * DMDL + h * DHD;
    nw = (which == 0) ? naq : nak;
  } else {
    src = ((which == 0) ? q0 : k0) + (size_t)(s - STXT) * DMDL + h * DHD;
    nw = (which == 0) ? nq : nk;
  }
  float2 x = *(const float2*)(src + 2 * l);
  float ss = x.x * x.x + x.y * x.y;
#pragma unroll
  for (int off = 1; off < 64; off <<= 1) ss += __shfl_xor(ss, off);
  float inv = rsqrtf(ss * (1.f / 128.f) + 1e-6f);
  float xw1 = x.x * inv * nw[2 * l];
  float xw2 = x.y * inv * nw[2 * l + 1];
  float c1 = rc[(size_t)s * DHD + 2 * l], c2 = rc[(size_t)s * DHD + 2 * l + 1];
  float s1 = rsn[(size_t)s * DHD + 2 * l], s2 = rsn[(size_t)s * DHD + 2 * l + 1];
  float y1 = xw1 * c1 - xw2 * s1;
  float y2 = xw2 * c2 + xw1 * s2;
  if (which == 0) { y1 *= 0.08838834764831845f; y2 *= 0.08838834764831845f; }
  unsigned short* dst = ((which == 0) ? Qp : Kp) + ((size_t)h * SEQ + s) * DHD + 2 * l;
  unsigned pk = (unsigned)f2bf(y1) | ((unsigned)f2bf(y2) << 16);
  *(unsigned*)dst = pk;
}

// ---------------------------------------------------------------------------
// V pack transposed: Vt_g[h][d][s] bf16 from f32 [s][3072]. grid (40,24).
// ---------------------------------------------------------------------------
__global__ __launch_bounds__(256) void vpackT_kernel(
    const float* __restrict__ v0, const float* __restrict__ ev,
    unsigned short* __restrict__ Vtg) {
  __shared__ unsigned short tile[64][128];
  const int t = threadIdx.x;
  const int s0 = blockIdx.x << 6;
  const int h = blockIdx.y;
  const float* src;
  int srow;
  if (s0 < STXT) { src = ev; srow = s0; } else { src = v0; srow = s0 - STXT; }
#pragma unroll
  for (int p = 0; p < 8; p++) {
    int idx4 = (p << 8) + t;
    int r = idx4 >> 5, c4 = idx4 & 31;
    float4 v = *(const float4*)(src + (size_t)(srow + r) * DMDL + h * DHD + (c4 << 2));
    u16x4 b = { f2bf(v.x), f2bf(v.y), f2bf(v.z), f2bf(v.w) };
    *(u16x4*)&tile[r][c4 << 2] = b;
  }
  __syncthreads();
  const int d = t >> 1, sc = (t & 1) << 5;
  unsigned short outv[32];
#pragma unroll
  for (int e = 0; e < 32; e++) outv[e] = tile[sc + e][d];
  unsigned short* dst = Vtg + ((size_t)h * DHD + d) * SEQ + s0 + sc;
#pragma unroll
  for (int q = 0; q < 4; q++)
    *(uint4*)(dst + (q << 3)) = *(uint4*)&outv[q << 3];
}

// ---------------------------------------------------------------------------
// Flash attention. grid (SEQ/64, HEADS), block 256 (4 waves x 16 q-rows).
// K [H][S][D]; V transposed [H][D][S]. All LDS tiles XOR-swizzled; K/V staged
// via global_load_lds with pre-swizzled global source. Q pre-scaled.
// ---------------------------------------------------------------------------
__global__ __launch_bounds__(256) void attn_kernel(
    const unsigned short* __restrict__ Qp, const unsigned short* __restrict__ Kp,
    const unsigned short* __restrict__ Vtg, float* __restrict__ attnb) {
  __shared__ unsigned short Klds[64][128];
  __shared__ unsigned short Vt[128][64];
  __shared__ unsigned short Plds[4][16][64];
  const int t = threadIdx.x, w = t >> 6, l = t & 63;
  const int l15 = l & 15, lg = l >> 4;
  const int h = blockIdx.y;
  const int q0r = blockIdx.x * 64;
  const unsigned short* Qh = Qp + (size_t)h * SEQ * DHD;
  const unsigned short* Kh = Kp + (size_t)h * SEQ * DHD;
  const unsigned short* Vh = Vtg + (size_t)h * DHD * SEQ;

  bf16x8 qf[4];
  {
    const unsigned short* qsrc = Qh + (size_t)(q0r + w * 16 + l15) * DHD + (lg << 3);
#pragma unroll
    for (int kf = 0; kf < 4; kf++) qf[kf] = *(const bf16x8*)(qsrc + kf * 32);
  }
  f32x4 o[8];
#pragma unroll
  for (int nc = 0; nc < 8; nc++) o[nc] = (f32x4){0.f, 0.f, 0.f, 0.f};
  float m[4] = {-1e30f, -1e30f, -1e30f, -1e30f};
  float sum[4] = {0.f, 0.f, 0.f, 0.f};

  for (int kv0 = 0; kv0 < SEQ; kv0 += 64) {
    __syncthreads();
#pragma unroll
    for (int g = 0; g < 4; g++) {
      const int jb = ((g << 2) + w) << 6;   // wave-uniform
      const int jl = jb + l;
      {
        const int row = jl >> 4, sl = jl & 15;
        const int col = (sl ^ (row & 7)) << 3;
        gload16(Kh + (size_t)(kv0 + row) * DHD + col, ((unsigned short*)Klds) + (size_t)jb * 8);
      }
      {
        const int d = jl >> 3, sl = jl & 7;
        const int col = (sl ^ (d & 7)) << 3;
        gload16(Vh + (size_t)d * SEQ + kv0 + col, ((unsigned short*)Vt) + (size_t)jb * 8);
      }
    }
    asm volatile("s_waitcnt vmcnt(0)" ::: "memory");
    __syncthreads();
    // QK^T
    f32x4 sacc[4];
    __builtin_amdgcn_s_setprio(1);
#pragma unroll
    for (int c = 0; c < 4; c++) {
      sacc[c] = (f32x4){0.f, 0.f, 0.f, 0.f};
      const int krow = c * 16 + l15;
#pragma unroll
      for (int kf = 0; kf < 4; kf++) {
        bf16x8 kb = *(const bf16x8*)&Klds[krow][(((kf << 2) + lg) ^ (krow & 7)) << 3];
        sacc[c] = __builtin_amdgcn_mfma_f32_16x16x32_bf16(qf[kf], kb, sacc[c], 0, 0, 0);
      }
    }
    __builtin_amdgcn_s_setprio(0);
    // online softmax per q-row (rows = lg*4 + j)
    float sc4[4];
#pragma unroll
    for (int j = 0; j < 4; j++) {
      float mx = fmaxf(fmaxf(sacc[0][j], sacc[1][j]), fmaxf(sacc[2][j], sacc[3][j]));
#pragma unroll
      for (int off = 1; off < 16; off <<= 1) mx = fmaxf(mx, __shfl_xor(mx, off));
      float mnew = fmaxf(m[j], mx);
      float scale = exp2f((m[j] - mnew) * 1.44269504f);
      float pv[4];
      float ps = 0.f;
#pragma unroll
      for (int c = 0; c < 4; c++) {
        pv[c] = exp2f((sacc[c][j] - mnew) * 1.44269504f);
        ps += pv[c];
      }
#pragma unroll
      for (int off = 1; off < 16; off <<= 1) ps += __shfl_xor(ps, off);
      sum[j] = sum[j] * scale + ps;
      m[j] = mnew;
      sc4[j] = scale;
      const int prow = (lg << 2) + j;
#pragma unroll
      for (int c = 0; c < 4; c++)
        Plds[w][prow][(c * 16 + l15) ^ ((prow & 7) << 3)] = f2bf(pv[c]);
    }
#pragma unroll
    for (int nc = 0; nc < 8; nc++) {
      o[nc][0] *= sc4[0]; o[nc][1] *= sc4[1]; o[nc][2] *= sc4[2]; o[nc][3] *= sc4[3];
    }
    // PV
    __builtin_amdgcn_s_setprio(1);
#pragma unroll
    for (int kf2 = 0; kf2 < 2; kf2++) {
      bf16x8 pa = *(const bf16x8*)&Plds[w][l15][(((kf2 << 2) + lg) ^ (l15 & 7)) << 3];
#pragma unroll
      for (int nc = 0; nc < 8; nc++) {
        const int vrow = nc * 16 + l15;
        bf16x8 vb = *(const bf16x8*)&Vt[vrow][(((kf2 << 2) + lg) ^ (vrow & 7)) << 3];
        o[nc] = __builtin_amdgcn_mfma_f32_16x16x32_bf16(pa, vb, o[nc], 0, 0, 0);
      }
    }
    __builtin_amdgcn_s_setprio(0);
  }
#pragma unroll
  for (int nc = 0; nc < 8; nc++)
#pragma unroll
    for (int j = 0; j < 4; j++) {
      const int row = q0r + w * 16 + (lg << 2) + j;
      const int col = h * DHD + nc * 16 + l15;
      attnb[(size_t)row * DMDL + col] = o[nc][j] / sum[j];
    }
}

// ---------------------------------------------------------------------------
// Bokeh LoRA down / up
// ---------------------------------------------------------------------------
__global__ __launch_bounds__(256) void bokeh_down_kernel(
    const float* __restrict__ bok, const float* __restrict__ kbd,
    const float* __restrict__ vbd, float* __restrict__ tkv) {
  const int t = threadIdx.x, w = t >> 6, l = t & 63;
  const int mat = blockIdx.x >> 2, j = blockIdx.x & 3;
  const float* dwn = mat ? vbd : kbd;
  const float* x = bok + (size_t)j * DMDL;
  float acc[16];
#pragma unroll
  for (int r = 0; r < 16; r++) acc[r] = 0.f;
  for (int k = t; k < DMDL; k += 256) {
    float xv = x[k];
#pragma unroll
    for (int r = 0; r < 16; r++) acc[r] += xv * dwn[r * DMDL + k];
  }
#pragma unroll
  for (int off = 1; off < 64; off <<= 1)
#pragma unroll
    for (int r = 0; r < 16; r++) acc[r] += __shfl_xor(acc[r], off);
  __shared__ float red[4][16];
  if (l == 0)
#pragma unroll
    for (int r = 0; r < 16; r++) red[w][r] = acc[r];
  __syncthreads();
  if (t < 16) tkv[(mat * 4 + j) * 16 + t] = red[0][t] + red[1][t] + red[2][t] + red[3][t];
}

__global__ __launch_bounds__(256) void bokeh_up_kernel(
    const float* __restrict__ tkv, const float* __restrict__ kbu,
    const float* __restrict__ vbu, float* __restrict__ kdvd) {
  const int idx = blockIdx.x * 256 + threadIdx.x;
  const int mat = idx / 12288, rem = idx % 12288;
  const int j = rem / DMDL, n = rem % DMDL;
  const float* up = mat ? vbu : kbu;
  const float* tv = tkv + (mat * 4 + j) * 16;
  float s = 0.f;
#pragma unroll
  for (int r = 0; r < 16; r++) s += tv[r] * up[(size_t)n * 16 + r];
  kdvd[(size_t)(mat * 4 + j) * DMDL + n] = s;
}

// ---------------------------------------------------------------------------
// Bokeh cross-attn + fused add + bf16 convert of attnb.
// grid SEQ*HEADS/4, one wave per (h,s).
// ---------------------------------------------------------------------------
__global__ __launch_bounds__(256) void cam_kernel(
    const unsigned short* __restrict__ Qp, const float* __restrict__ kdvd,
    const float* __restrict__ attnb, unsigned short* __restrict__ attnb_bf) {
  const int t = threadIdx.x, w = t >> 6, l = t & 63;
  const int id = blockIdx.x * 4 + w;
  const int h = id / SEQ, s = id % SEQ;
  const unsigned short* q = Qp + ((size_t)h * SEQ + s) * DHD + 2 * l;
  unsigned qp = *(const unsigned*)q;
  float q1 = bf2f((unsigned short)(qp & 0xffffu));
  float q2 = bf2f((unsigned short)(qp >> 16));
  float p[4];
#pragma unroll
  for (int j = 0; j < 4; j++) {
    const float* kd = kdvd + (size_t)j * DMDL + h * DHD + 2 * l;
    float d = q1 * kd[0] + q2 * kd[1];
#pragma unroll
    for (int off = 1; off < 64; off <<= 1) d += __shfl_xor(d, off);
    p[j] = d;
  }
  float mx = fmaxf(fmaxf(p[0], p[1]), fmaxf(p[2], p[3]));
  float ps = 0.f;
#pragma unroll
  for (int j = 0; j < 4; j++) { p[j] = exp2f((p[j] - mx) * 1.44269504f); ps += p[j]; }
  float rinv = 1.f / ps;
  float o1 = 0.f, o2 = 0.f;
#pragma unroll
  for (int j = 0; j < 4; j++) {
    const float* vd = kdvd + (size_t)(4 + j) * DMDL + h * DHD + 2 * l;
    o1 += p[j] * vd[0];
    o2 += p[j] * vd[1];
  }
  const size_t idx = (size_t)s * DMDL + h * DHD + 2 * l;
  float a1 = attnb[idx] + o1 * rinv;
  float a2 = attnb[idx + 1] + o2 * rinv;
  unsigned pk = (unsigned)f2bf(a1) | ((unsigned)f2bf(a2) << 16);
  *(unsigned*)(attnb_bf + idx) = pk;
}

// ---------------------------------------------------------------------------
extern "C" void kernel_launch(void* const* d_in, const int* in_sizes, int n_in,
                              void* d_out, int out_size, void* d_ws, size_t ws_size,
                              hipStream_t stream) {
  (void)in_sizes; (void)n_in; (void)out_size; (void)ws_size;
  const float* hs  = (const float*)d_in[0];
  const float* enc = (const float*)d_in[1];
  const float* bok = (const float*)d_in[2];
  const float* rc  = (const float*)d_in[3];
  const float* rsn = (const float*)d_in[4];
  const float* Wq  = (const float*)d_in[5];
  const float* Wk  = (const float*)d_in[6];
  const float* Wv  = (const float*)d_in[7];
  const float* Waq = (const float*)d_in[8];
  const float* Wak = (const float*)d_in[9];
  const float* Wav = (const float*)d_in[10];
  const float* Wo  = (const float*)d_in[11];
  const float* Wao = (const float*)d_in[12];
  const float* bq  = (const float*)d_in[13];
  const float* bk  = (const float*)d_in[14];
  const float* bv  = (const float*)d_in[15];
  const float* baq = (const float*)d_in[16];
  const float* bak = (const float*)d_in[17];
  const float* bav = (const float*)d_in[18];
  const float* bo  = (const float*)d_in[19];
  const float* bao = (const float*)d_in[20];
  const float* nq  = (const float*)d_in[21];
  const float* nk  = (const float*)d_in[22];
  const float* naq = (const float*)d_in[23];
  const float* nak = (const float*)d_in[24];
  const float* kbd = (const float*)d_in[25];
  const float* vbd = (const float*)d_in[26];
  const float* qad = (const float*)d_in[27];
  const float* kad = (const float*)d_in[28];
  const float* kbu = (const float*)d_in[29];
  const float* vbu = (const float*)d_in[30];
  const float* qau = (const float*)d_in[31];
  const float* kau = (const float*)d_in[32];

  char* ws = (char*)d_ws;
  float* q0   = (float*)(ws + 0);                     // 25165824
  float* k0   = (float*)(ws + 25165824);
  float* v0   = (float*)(ws + 50331648);
  float* eq   = (float*)(ws + 75497472);              // 6291456
  float* ek   = (float*)(ws + 81788928);
  float* ev   = (float*)(ws + 88080384);
  float* tmpq = (float*)(ws + 94371840);
  float* tmpk = (float*)(ws + 94502912);
  float* tkv  = (float*)(ws + 94633984);
  float* kdvd = (float*)(ws + 94638080);
  unsigned short* Qp  = (unsigned short*)(ws + 94736384);   // 15728640
  unsigned short* Kp  = (unsigned short*)(ws + 110465024);  // 15728640
  unsigned short* Vtg = (unsigned short*)(ws + 126193664);  // 15728640
  float* attnb = (float*)(ws + 141922304);                  // 31457280
  unsigned short* hs_bf  = (unsigned short*)(ws + 173379584); // 12582912
  unsigned short* enc_bf = (unsigned short*)(ws + 185962496); // 3145728
  unsigned short* w_bf   = (unsigned short*)(ws + 189108224); // 18874368
  unsigned short* attnb_bf = Kp;  // alias: Kp dead after attn_kernel

  float* out_img = (float*)d_out;
  float* out_enc = (float*)d_out + (size_t)2048 * 3072;

  dim3 blk(256);
  const int gW = 9216;   // 3072*3072/1024
  const int gBig = 384;  // (2048/128)*(3072/128)
  const int gSm  = 96;   // (512/128)*(3072/128)

  convf2b_kernel<<<6144, blk, 0, stream>>>(hs, hs_bf);
  convf2b_kernel<<<1536, blk, 0, stream>>>(enc, enc_bf);

  convf2b_kernel<<<gW, blk, 0, stream>>>(Wq, w_bf);
  gemm_bf16_kernel<<<gBig, blk, 0, stream>>>(hs_bf, w_bf, bq, q0, 2048, DMDL, DMDL);
  convf2b_kernel<<<gW, blk, 0, stream>>>(Wk, w_bf);
  gemm_bf16_kernel<<<gBig, blk, 0, stream>>>(hs_bf, w_bf, bk, k0, 2048, DMDL, DMDL);
  convf2b_kernel<<<gW, blk, 0, stream>>>(Wv, w_bf);
  gemm_bf16_kernel<<<gBig, blk, 0, stream>>>(hs_bf, w_bf, bv, v0, 2048, DMDL, DMDL);
  convf2b_kernel<<<gW, blk, 0, stream>>>(Waq, w_bf);
  gemm_bf16_kernel<<<gSm, blk, 0, stream>>>(enc_bf, w_bf, baq, eq, 512, DMDL, DMDL);
  convf2b_kernel<<<gW, blk, 0, stream>>>(Wak, w_bf);
  gemm_bf16_kernel<<<gSm, blk, 0, stream>>>(enc_bf, w_bf, bak, ek, 512, DMDL, DMDL);
  convf2b_kernel<<<gW, blk, 0, stream>>>(Wav, w_bf);
  gemm_bf16_kernel<<<gSm, blk, 0, stream>>>(enc_bf, w_bf, bav, ev, 512, DMDL, DMDL);

  lora_down_kernel<<<2048, blk, 0, stream>>>(q0, qad, tmpq);
  lora_down_kernel<<<2048, blk, 0, stream>>>(k0, kad, tmpk);
  lora_up_kernel<<<24576, blk, 0, stream>>>(q0, tmpq, qau);
  lora_up_kernel<<<24576, blk, 0, stream>>>(k0, tmpk, kau);

  pack_kernel<<<dim3(SEQ / 4, HEADS, 2), blk, 0, stream>>>(
      q0, k0, eq, ek, nq, nk, naq, nak, rc, rsn, Qp, Kp);
  vpackT_kernel<<<dim3(SEQ / 64, HEADS), blk, 0, stream>>>(v0, ev, Vtg);

  attn_kernel<<<dim3(SEQ / 64, HEADS), blk, 0, stream>>>(Qp, Kp, Vtg, attnb);

  bokeh_down_kernel<<<8, blk, 0, stream>>>(bok, kbd, vbd, tkv);
  bokeh_up_kernel<<<96, blk, 0, stream>>>(tkv, kbu, vbu, kdvd);
  cam_kernel<<<SEQ * HEADS / 4, blk, 0, stream>>>(Qp, kdvd, attnb, attnb_bf);

  convf2b_kernel<<<gW, blk, 0, stream>>>(Wo, w_bf);
  gemm_bf16_kernel<<<gBig, blk, 0, stream>>>(attnb_bf + (size_t)STXT * DMDL, w_bf, bo,
                                             out_img, 2048, DMDL, DMDL);
  convf2b_kernel<<<gW, blk, 0, stream>>>(Wao, w_bf);
  gemm_bf16_kernel<<<gSm, blk, 0, stream>>>(attnb_bf, w_bf, bao, out_enc, 512, DMDL, DMDL);
}

// Round 3
// 740.187 us; speedup vs baseline: 2.1544x; 1.3507x over previous
//
#include <hip/hip_runtime.h>

#define DMDL 3072
#define SEQ  2560
#define STXT 512
#define HEADS 24
#define DHD  128
#define WB9 9437184  // 3072*3072

typedef float f32x4 __attribute__((ext_vector_type(4)));
typedef __bf16 bf16x8 __attribute__((ext_vector_type(8)));
typedef unsigned short u16x4 __attribute__((ext_vector_type(4)));

static __device__ __forceinline__ unsigned short f2bf(float f) {
  unsigned u = __float_as_uint(f);
  u += 0x7fffu + ((u >> 16) & 1u);
  return (unsigned short)(u >> 16);
}

static __device__ __forceinline__ float fexp2(float x) {
  return __builtin_amdgcn_exp2f(x);
}

// async global->LDS, 16B/lane; LDS dest wave-uniform base + lane*16.
static __device__ __forceinline__ void gload16(const unsigned short* g, unsigned short* l) {
  __builtin_amdgcn_global_load_lds(
      (const __attribute__((address_space(1))) unsigned int*)g,
      (__attribute__((address_space(3))) unsigned int*)l, 16, 0, 0);
}

// ---------------------------------------------------------------------------
// f32 -> bf16 convert, grid = n/1024
// ---------------------------------------------------------------------------
__global__ __launch_bounds__(256) void convf2b_kernel(
    const float* __restrict__ src, unsigned short* __restrict__ dst) {
  const int idx4 = blockIdx.x * 256 + threadIdx.x;
  float4 v = *(const float4*)(src + (size_t)idx4 * 4);
  u16x4 b = { f2bf(v.x), f2bf(v.y), f2bf(v.z), f2bf(v.w) };
  *(u16x4*)(dst + (size_t)idx4 * 4) = b;
}

// batched weight conv: up to 3 srcs (blockIdx.y selects), each 3072x3072
__global__ __launch_bounds__(256) void convw_kernel(
    const float* __restrict__ s0, const float* __restrict__ s1,
    const float* __restrict__ s2, unsigned short* __restrict__ dst) {
  const float* src = (blockIdx.y == 0) ? s0 : (blockIdx.y == 1) ? s1 : s2;
  const size_t idx4 = (size_t)blockIdx.x * 256 + threadIdx.x;
  float4 v = *(const float4*)(src + idx4 * 4);
  u16x4 b = { f2bf(v.x), f2bf(v.y), f2bf(v.z), f2bf(v.w) };
  *(u16x4*)(dst + (size_t)blockIdx.y * WB9 + idx4 * 4) = b;
}

// ---------------------------------------------------------------------------
// Shared GEMM body: C[128 rows @row0][128 cols @col0(local)] over K=3072.
// A bf16 [M][3072], Bw bf16 [3072+][3072] (row = out col), C f32 ldc=3072.
// ---------------------------------------------------------------------------
__device__ __forceinline__ void gemm_body(
    const unsigned short* __restrict__ A, const unsigned short* __restrict__ Bw,
    const float* __restrict__ bias, float* __restrict__ C,
    int row0, int col0) {
  __shared__ unsigned short Al[128][64];
  __shared__ unsigned short Bl[128][64];
  const int t = threadIdx.x, w = t >> 6, l = t & 63;
  const int wr = (w >> 1) << 6, wc = (w & 1) << 6;
  const int l15 = l & 15, lg = l >> 4;
  f32x4 acc[4][4];
#pragma unroll
  for (int i = 0; i < 4; i++)
#pragma unroll
    for (int j = 0; j < 4; j++) acc[i][j] = (f32x4){0.f, 0.f, 0.f, 0.f};

  for (int k0 = 0; k0 < DMDL; k0 += 64) {
    __syncthreads();
#pragma unroll
    for (int g = 0; g < 4; g++) {
      const int jb = ((w << 2) + g) << 6;
      const int jl = jb + l;
      const int row = jl >> 3, sl = jl & 7;
      const int col = ((sl ^ (row & 7)) << 3);
      gload16(A  + (size_t)(row0 + row) * DMDL + k0 + col, ((unsigned short*)Al) + (size_t)jb * 8);
      gload16(Bw + (size_t)(col0 + row) * DMDL + k0 + col, ((unsigned short*)Bl) + (size_t)jb * 8);
    }
    asm volatile("s_waitcnt vmcnt(0)" ::: "memory");
    __syncthreads();
#pragma unroll
    for (int kf = 0; kf < 2; kf++) {
      bf16x8 af[4], bfr[4];
#pragma unroll
      for (int i = 0; i < 4; i++) {
        const int ra = wr + (i << 4) + l15;
        af[i]  = *(const bf16x8*)&Al[ra][(((kf << 2) + lg) ^ (ra & 7)) << 3];
        const int rb = wc + (i << 4) + l15;
        bfr[i] = *(const bf16x8*)&Bl[rb][(((kf << 2) + lg) ^ (rb & 7)) << 3];
      }
      __builtin_amdgcn_s_setprio(1);
#pragma unroll
      for (int i = 0; i < 4; i++)
#pragma unroll
        for (int j = 0; j < 4; j++)
          acc[i][j] = __builtin_amdgcn_mfma_f32_16x16x32_bf16(af[i], bfr[j], acc[i][j], 0, 0, 0);
      __builtin_amdgcn_s_setprio(0);
    }
  }
#pragma unroll
  for (int i = 0; i < 4; i++)
#pragma unroll
    for (int j = 0; j < 4; j++) {
      const int col = col0 + wc + (j << 4) + l15;
      const float bb = bias[col];
      const int rbase = row0 + wr + (i << 4) + (lg << 2);
#pragma unroll
      for (int r2 = 0; r2 < 4; r2++)
        C[(size_t)(rbase + r2) * DMDL + col] = acc[i][j][r2] + bb;
    }
}

// Fused 3-output GEMM: Bw = w3 (3 stacked 3072x3072), grid = (M/128)*72
__global__ __launch_bounds__(256) void gemm3_kernel(
    const unsigned short* __restrict__ A, const unsigned short* __restrict__ w3,
    const float* __restrict__ b0, const float* __restrict__ b1, const float* __restrict__ b2,
    float* __restrict__ c0, float* __restrict__ c1, float* __restrict__ c2, int M) {
  const int nwg = (M >> 7) * 72;
  const int cpx = nwg >> 3;
  const int sid = (blockIdx.x & 7) * cpx + (blockIdx.x >> 3);
  const int by = sid / 72, bxx = sid - by * 72;
  const int grp = bxx / 24, bx = bxx - grp * 24;
  const unsigned short* Bw = w3 + (size_t)grp * WB9;
  const float* bias = (grp == 0) ? b0 : (grp == 1) ? b1 : b2;
  float* C = (grp == 0) ? c0 : (grp == 1) ? c1 : c2;
  gemm_body(A, Bw, bias, C, by << 7, bx << 7);
}

// Grouped output GEMM: blocks 0..383 img (Wo), 384..479 enc (Wao). grid 480.
__global__ __launch_bounds__(256) void gemm_out_kernel(
    const unsigned short* __restrict__ attnbf, const unsigned short* __restrict__ w3,
    const float* __restrict__ bo, const float* __restrict__ bao,
    float* __restrict__ out) {
  const int sid = (blockIdx.x & 7) * 60 + (blockIdx.x >> 3);
  if (sid < 384) {
    const int by = sid / 24, bx = sid - by * 24;
    gemm_body(attnbf + (size_t)STXT * DMDL, w3, bo, out, by << 7, bx << 7);
  } else {
    const int s2 = sid - 384;
    const int by = s2 / 24, bx = s2 - by * 24;
    gemm_body(attnbf, w3 + WB9, bao, out + (size_t)2048 * DMDL, by << 7, bx << 7);
  }
}

// ---------------------------------------------------------------------------
// LoRA down (q and k batched via blockIdx.y): tmp[M][16]
// ---------------------------------------------------------------------------
__global__ __launch_bounds__(256) void lora_down2_kernel(
    const float* __restrict__ q0, const float* __restrict__ k0,
    const float* __restrict__ qad, const float* __restrict__ kad,
    float* __restrict__ tmpq, float* __restrict__ tmpk) {
  const int t = threadIdx.x, w = t >> 6, l = t & 63;
  const int m = blockIdx.x;
  const float* X = blockIdx.y ? k0 : q0;
  const float* dwn = blockIdx.y ? kad : qad;
  float* tmp = blockIdx.y ? tmpk : tmpq;
  const float* x = X + (size_t)m * DMDL;
  float acc[16];
#pragma unroll
  for (int r = 0; r < 16; r++) acc[r] = 0.f;
  for (int k = t; k < DMDL; k += 256) {
    float xv = x[k];
#pragma unroll
    for (int r = 0; r < 16; r++) acc[r] += xv * dwn[r * DMDL + k];
  }
#pragma unroll
  for (int off = 1; off < 64; off <<= 1)
#pragma unroll
    for (int r = 0; r < 16; r++) acc[r] += __shfl_xor(acc[r], off);
  __shared__ float red[4][16];
  if (l == 0)
#pragma unroll
    for (int r = 0; r < 16; r++) red[w][r] = acc[r];
  __syncthreads();
  if (t < 16) tmp[(size_t)m * 16 + t] = red[0][t] + red[1][t] + red[2][t] + red[3][t];
}

// ---------------------------------------------------------------------------
// Pack q,k: (+LoRA-up for image rows) + RMSNorm + RoPE + scale + bf16
// Q scale includes log2e fold: 1/sqrt(128)*log2(e).
// grid (SEQ/4, HEADS, 2), wave per s.
// ---------------------------------------------------------------------------
#define QSCALE 0.12751743f
__global__ __launch_bounds__(256) void pack_kernel(
    const float* __restrict__ q0, const float* __restrict__ k0,
    const float* __restrict__ eq, const float* __restrict__ ek,
    const float* __restrict__ tmpq, const float* __restrict__ tmpk,
    const float* __restrict__ qau, const float* __restrict__ kau,
    const float* __restrict__ nq, const float* __restrict__ nk,
    const float* __restrict__ naq, const float* __restrict__ nak,
    const float* __restrict__ rc, const float* __restrict__ rsn,
    unsigned short* __restrict__ Qp, unsigned short* __restrict__ Kp) {
  const int t = threadIdx.x, w = t >> 6, l = t & 63;
  const int s = blockIdx.x * 4 + w;
  const int h = blockIdx.y;
  const int which = blockIdx.z;
  const int n = h * DHD + 2 * l;
  float2 x;
  const float* nw;
  if (s < STXT) {
    x = *(const float2*)(((which == 0) ? eq : ek) + (size_t)s * DMDL + n);
    nw = (which == 0) ? naq : nak;
  } else {
    x = *(const float2*)(((which == 0) ? q0 : k0) + (size_t)(s - STXT) * DMDL + n);
    nw = (which == 0) ? nq : nk;
    const float* tv = ((which == 0) ? tmpq : tmpk) + (size_t)(s - STXT) * 16;
    const float* uv = ((which == 0) ? qau : kau) + (size_t)n * 16;
    float l1 = 0.f, l2 = 0.f;
#pragma unroll
    for (int r = 0; r < 16; r++) { l1 += tv[r] * uv[r]; l2 += tv[r] * uv[16 + r]; }
    x.x += l1; x.y += l2;
  }
  float ss = x.x * x.x + x.y * x.y;
#pragma unroll
  for (int off = 1; off < 64; off <<= 1) ss += __shfl_xor(ss, off);
  float inv = rsqrtf(ss * (1.f / 128.f) + 1e-6f);
  float xw1 = x.x * inv * nw[2 * l];
  float xw2 = x.y * inv * nw[2 * l + 1];
  float c1 = rc[(size_t)s * DHD + 2 * l], c2 = rc[(size_t)s * DHD + 2 * l + 1];
  float s1 = rsn[(size_t)s * DHD + 2 * l], s2 = rsn[(size_t)s * DHD + 2 * l + 1];
  float y1 = xw1 * c1 - xw2 * s1;
  float y2 = xw2 * c2 + xw1 * s2;
  if (which == 0) { y1 *= QSCALE; y2 *= QSCALE; }
  unsigned short* dst = ((which == 0) ? Qp : Kp) + ((size_t)h * SEQ + s) * DHD + 2 * l;
  unsigned pk = (unsigned)f2bf(y1) | ((unsigned)f2bf(y2) << 16);
  *(unsigned*)dst = pk;
}

// ---------------------------------------------------------------------------
// V pack transposed: Vtg[h][d][s] bf16. grid (40,24).
// ---------------------------------------------------------------------------
__global__ __launch_bounds__(256) void vpackT_kernel(
    const float* __restrict__ v0, const float* __restrict__ ev,
    unsigned short* __restrict__ Vtg) {
  __shared__ unsigned short tile[64][136];
  const int t = threadIdx.x;
  const int s0 = blockIdx.x << 6;
  const int h = blockIdx.y;
  const float* src;
  int srow;
  if (s0 < STXT) { src = ev; srow = s0; } else { src = v0; srow = s0 - STXT; }
#pragma unroll
  for (int p = 0; p < 8; p++) {
    int idx4 = (p << 8) + t;
    int r = idx4 >> 5, c4 = idx4 & 31;
    float4 v = *(const float4*)(src + (size_t)(srow + r) * DMDL + h * DHD + (c4 << 2));
    u16x4 b = { f2bf(v.x), f2bf(v.y), f2bf(v.z), f2bf(v.w) };
    *(u16x4*)&tile[r][c4 << 2] = b;
  }
  __syncthreads();
  const int d = t >> 1, sc = (t & 1) << 5;
  unsigned short outv[32];
#pragma unroll
  for (int e = 0; e < 32; e++) outv[e] = tile[sc + e][d];
  unsigned short* dst = Vtg + ((size_t)h * DHD + d) * SEQ + s0 + sc;
#pragma unroll
  for (int q = 0; q < 4; q++)
    *(uint4*)(dst + (q << 3)) = *(uint4*)&outv[q << 3];
}

// ---------------------------------------------------------------------------
// Bokeh LoRA down / up
// ---------------------------------------------------------------------------
__global__ __launch_bounds__(256) void bokeh_down_kernel(
    const float* __restrict__ bok, const float* __restrict__ kbd,
    const float* __restrict__ vbd, float* __restrict__ tkv) {
  const int t = threadIdx.x, w = t >> 6, l = t & 63;
  const int mat = blockIdx.x >> 2, j = blockIdx.x & 3;
  const float* dwn = mat ? vbd : kbd;
  const float* x = bok + (size_t)j * DMDL;
  float acc[16];
#pragma unroll
  for (int r = 0; r < 16; r++) acc[r] = 0.f;
  for (int k = t; k < DMDL; k += 256) {
    float xv = x[k];
#pragma unroll
    for (int r = 0; r < 16; r++) acc[r] += xv * dwn[r * DMDL + k];
  }
#pragma unroll
  for (int off = 1; off < 64; off <<= 1)
#pragma unroll
    for (int r = 0; r < 16; r++) acc[r] += __shfl_xor(acc[r], off);
  __shared__ float red[4][16];
  if (l == 0)
#pragma unroll
    for (int r = 0; r < 16; r++) red[w][r] = acc[r];
  __syncthreads();
  if (t < 16) tkv[(mat * 4 + j) * 16 + t] = red[0][t] + red[1][t] + red[2][t] + red[3][t];
}

__global__ __launch_bounds__(256) void bokeh_up_kernel(
    const float* __restrict__ tkv, const float* __restrict__ kbu,
    const float* __restrict__ vbu, float* __restrict__ kdvd) {
  const int idx = blockIdx.x * 256 + threadIdx.x;
  const int mat = idx / 12288, rem = idx % 12288;
  const int j = rem / DMDL, n = rem % DMDL;
  const float* up = mat ? vbu : kbu;
  const float* tv = tkv + (mat * 4 + j) * 16;
  float s = 0.f;
#pragma unroll
  for (int r = 0; r < 16; r++) s += tv[r] * up[(size_t)n * 16 + r];
  kdvd[(size_t)(mat * 4 + j) * DMDL + n] = s;
}

// ---------------------------------------------------------------------------
// Flash attention + fused bokeh cross-attn epilogue -> bf16 out.
// grid (SEQ/64, HEADS), 4 waves x 16 q-rows, KVBLK=128.
// Q pre-scaled by (1/sqrt(128))*log2e -> exp2 directly. Defer-max (THR=8).
// ---------------------------------------------------------------------------
__global__ __launch_bounds__(256) void attn_kernel(
    const unsigned short* __restrict__ Qp, const unsigned short* __restrict__ Kp,
    const unsigned short* __restrict__ Vtg, const float* __restrict__ kdvd,
    unsigned short* __restrict__ attnbf) {
  __shared__ unsigned short Klds[128][128];
  __shared__ unsigned short Vt[128][128];
  __shared__ unsigned short Plds[4][16][128];
  const int t = threadIdx.x, w = t >> 6, l = t & 63;
  const int l15 = l & 15, lg = l >> 4;
  const int h = blockIdx.y;
  const int q0r = blockIdx.x * 64;
  const unsigned short* Qh = Qp + (size_t)h * SEQ * DHD;
  const unsigned short* Kh = Kp + (size_t)h * SEQ * DHD;
  const unsigned short* Vh = Vtg + (size_t)h * DHD * SEQ;

  bf16x8 qf[4];
  {
    const unsigned short* qsrc = Qh + (size_t)(q0r + w * 16 + l15) * DHD + (lg << 3);
#pragma unroll
    for (int kf = 0; kf < 4; kf++) qf[kf] = *(const bf16x8*)(qsrc + kf * 32);
  }
  f32x4 o[8];
#pragma unroll
  for (int nc = 0; nc < 8; nc++) o[nc] = (f32x4){0.f, 0.f, 0.f, 0.f};
  float m[4] = {-1e30f, -1e30f, -1e30f, -1e30f};
  float sum[4] = {0.f, 0.f, 0.f, 0.f};

  for (int kv0 = 0; kv0 < SEQ; kv0 += 128) {
    __syncthreads();
#pragma unroll
    for (int g = 0; g < 8; g++) {
      const int jb = ((g << 2) + w) << 6;
      const int jl = jb + l;
      const int row = jl >> 4, sl = jl & 15;
      const int col = (sl ^ (row & 7)) << 3;
      gload16(Kh + (size_t)(kv0 + row) * DHD + col, ((unsigned short*)Klds) + (size_t)jb * 8);
      gload16(Vh + (size_t)row * SEQ + kv0 + col, ((unsigned short*)Vt) + (size_t)jb * 8);
    }
    asm volatile("s_waitcnt vmcnt(0)" ::: "memory");
    __syncthreads();
    // QK^T (scores already in log2 units)
    f32x4 sacc[8];
    __builtin_amdgcn_s_setprio(1);
#pragma unroll
    for (int c = 0; c < 8; c++) {
      sacc[c] = (f32x4){0.f, 0.f, 0.f, 0.f};
      const int krow = c * 16 + l15;
#pragma unroll
      for (int kf = 0; kf < 4; kf++) {
        bf16x8 kb = *(const bf16x8*)&Klds[krow][(((kf << 2) + lg) ^ (krow & 7)) << 3];
        sacc[c] = __builtin_amdgcn_mfma_f32_16x16x32_bf16(qf[kf], kb, sacc[c], 0, 0, 0);
      }
    }
    __builtin_amdgcn_s_setprio(0);
    // tile max per row
    float mxv[4];
#pragma unroll
    for (int j = 0; j < 4; j++) {
      float mx = sacc[0][j];
#pragma unroll
      for (int c = 1; c < 8; c++) mx = fmaxf(mx, sacc[c][j]);
#pragma unroll
      for (int off = 1; off < 16; off <<= 1) mx = fmaxf(mx, __shfl_xor(mx, off));
      mxv[j] = mx;
    }
    int ok = 1;
#pragma unroll
    for (int j = 0; j < 4; j++) ok &= (mxv[j] <= m[j] + 8.f);
    const bool skip = __all(ok);
    float sc4[4];
#pragma unroll
    for (int j = 0; j < 4; j++) {
      const float mnew = skip ? m[j] : fmaxf(m[j], mxv[j]);
      const int prow = (lg << 2) + j;
      unsigned short* pp = &Plds[w][prow][0];
      float ps = 0.f;
#pragma unroll
      for (int c = 0; c < 8; c++) {
        float pv = fexp2(sacc[c][j] - mnew);
        ps += pv;
        pp[(c * 16 + l15) ^ ((prow & 7) << 3)] = f2bf(pv);
      }
#pragma unroll
      for (int off = 1; off < 16; off <<= 1) ps += __shfl_xor(ps, off);
      if (!skip) {
        float sc = fexp2(m[j] - mnew);
        sum[j] = sum[j] * sc + ps;
        m[j] = mnew;
        sc4[j] = sc;
      } else {
        sum[j] += ps;
      }
    }
    if (!skip) {
#pragma unroll
      for (int nc = 0; nc < 8; nc++) {
        o[nc][0] *= sc4[0]; o[nc][1] *= sc4[1]; o[nc][2] *= sc4[2]; o[nc][3] *= sc4[3];
      }
    }
    // PV
    __builtin_amdgcn_s_setprio(1);
#pragma unroll
    for (int kf2 = 0; kf2 < 4; kf2++) {
      bf16x8 pa = *(const bf16x8*)&Plds[w][l15][(((kf2 << 2) + lg) ^ (l15 & 7)) << 3];
#pragma unroll
      for (int nc = 0; nc < 8; nc++) {
        const int vrow = nc * 16 + l15;
        bf16x8 vb = *(const bf16x8*)&Vt[vrow][(((kf2 << 2) + lg) ^ (vrow & 7)) << 3];
        o[nc] = __builtin_amdgcn_mfma_f32_16x16x32_bf16(pa, vb, o[nc], 0, 0, 0);
      }
    }
    __builtin_amdgcn_s_setprio(0);
  }

  // ---- epilogue: bokeh cross-attn (4 keys) + normalize + bf16 store ----
  __syncthreads();
  float* kdl = (float*)&Klds[0][0];  // [8][128] f32: kd rows 0..3, vd rows 4..7
  {
    const int j8 = t >> 5, d4 = (t & 31) << 2;
    *(float4*)&kdl[j8 * 128 + d4] = *(const float4*)(kdvd + (size_t)j8 * DMDL + h * DHD + d4);
  }
  __syncthreads();
  float q32[4][8];
#pragma unroll
  for (int kf = 0; kf < 4; kf++)
#pragma unroll
    for (int r = 0; r < 8; r++) q32[kf][r] = (float)qf[kf][r];
  float pj[4];
#pragma unroll
  for (int jb = 0; jb < 4; jb++) {
    float d = 0.f;
#pragma unroll
    for (int kf = 0; kf < 4; kf++)
#pragma unroll
      for (int r = 0; r < 8; r++)
        d += q32[kf][r] * kdl[jb * 128 + (kf << 5) + (lg << 3) + r];
    d += __shfl_xor(d, 16);
    d += __shfl_xor(d, 32);
    pj[jb] = d;  // log2-domain score for row l15
  }
  float cm = fmaxf(fmaxf(pj[0], pj[1]), fmaxf(pj[2], pj[3]));
  float cs = 0.f;
#pragma unroll
  for (int jb = 0; jb < 4; jb++) { pj[jb] = fexp2(pj[jb] - cm); cs += pj[jb]; }
  float ci = 1.f / cs;
#pragma unroll
  for (int jb = 0; jb < 4; jb++) pj[jb] *= ci;
  float* pnl = kdl + 1024 + (w << 6);  // 64 f32 per wave
  if (lg == 0) {
#pragma unroll
    for (int jb = 0; jb < 4; jb++) pnl[l15 * 4 + jb] = pj[jb];
  }
  __syncthreads();
  float rinv[4];
#pragma unroll
  for (int j = 0; j < 4; j++) rinv[j] = 1.f / sum[j];
  float pr[4][4];
#pragma unroll
  for (int j = 0; j < 4; j++)
#pragma unroll
    for (int jb = 0; jb < 4; jb++) pr[j][jb] = pnl[(((lg << 2) + j) << 2) + jb];
  const float* vdl = kdl + 512;
#pragma unroll
  for (int nc = 0; nc < 8; nc++) {
    const int col = (nc << 4) + l15;
#pragma unroll
    for (int j = 0; j < 4; j++) {
      float cam = pr[j][0] * vdl[col] + pr[j][1] * vdl[128 + col] +
                  pr[j][2] * vdl[256 + col] + pr[j][3] * vdl[384 + col];
      float outv = o[nc][j] * rinv[j] + cam;
      const int row = q0r + (w << 4) + (lg << 2) + j;
      attnbf[(size_t)row * DMDL + h * DHD + col] = f2bf(outv);
    }
  }
}

// ---------------------------------------------------------------------------
extern "C" void kernel_launch(void* const* d_in, const int* in_sizes, int n_in,
                              void* d_out, int out_size, void* d_ws, size_t ws_size,
                              hipStream_t stream) {
  (void)in_sizes; (void)n_in; (void)out_size; (void)ws_size;
  const float* hs  = (const float*)d_in[0];
  const float* enc = (const float*)d_in[1];
  const float* bok = (const float*)d_in[2];
  const float* rc  = (const float*)d_in[3];
  const float* rsn = (const float*)d_in[4];
  const float* Wq  = (const float*)d_in[5];
  const float* Wk  = (const float*)d_in[6];
  const float* Wv  = (const float*)d_in[7];
  const float* Waq = (const float*)d_in[8];
  const float* Wak = (const float*)d_in[9];
  const float* Wav = (const float*)d_in[10];
  const float* Wo  = (const float*)d_in[11];
  const float* Wao = (const float*)d_in[12];
  const float* bq  = (const float*)d_in[13];
  const float* bk  = (const float*)d_in[14];
  const float* bv  = (const float*)d_in[15];
  const float* baq = (const float*)d_in[16];
  const float* bak = (const float*)d_in[17];
  const float* bav = (const float*)d_in[18];
  const float* bo  = (const float*)d_in[19];
  const float* bao = (const float*)d_in[20];
  const float* nq  = (const float*)d_in[21];
  const float* nk  = (const float*)d_in[22];
  const float* naq = (const float*)d_in[23];
  const float* nak = (const float*)d_in[24];
  const float* kbd = (const float*)d_in[25];
  const float* vbd = (const float*)d_in[26];
  const float* qad = (const float*)d_in[27];
  const float* kad = (const float*)d_in[28];
  const float* kbu = (const float*)d_in[29];
  const float* vbu = (const float*)d_in[30];
  const float* qau = (const float*)d_in[31];
  const float* kau = (const float*)d_in[32];

  char* ws = (char*)d_ws;
  unsigned short* w3     = (unsigned short*)(ws + 0);           // 56,623,104
  unsigned short* hs_bf  = (unsigned short*)(ws + 56623104);    // 12,582,912
  unsigned short* enc_bf = (unsigned short*)(ws + 69206016);    //  3,145,728
  float* q0   = (float*)(ws + 72351744);                        // 25,165,824
  float* k0   = (float*)(ws + 97517568);                        // 25,165,824
  float* v0   = (float*)(ws + 122683392);                       // 25,165,824
  float* eq   = (float*)(ws + 147849216);                       //  6,291,456
  float* ek   = (float*)(ws + 154140672);
  float* ev   = (float*)(ws + 160432128);
  float* tmpq = (float*)(ws + 166723584);
  float* tmpk = (float*)(ws + 166854656);
  float* tkv  = (float*)(ws + 166985728);
  float* kdvd = (float*)(ws + 166986240);
  unsigned short* Qp  = (unsigned short*)(ws + 167084544);      // 15,728,640
  unsigned short* Kp  = (unsigned short*)(ws + 182813184);      // 15,728,640 -> 198,541,824
  unsigned short* Vtg = (unsigned short*)(ws + 72351744);       // alias q0 (dead after pack)
  unsigned short* attnbf = (unsigned short*)(ws + 122683392);   // alias v0 (dead after vpackT)

  float* out = (float*)d_out;  // img [2048][3072] then enc [512][3072]

  dim3 blk(256);

  convf2b_kernel<<<6144, blk, 0, stream>>>(hs, hs_bf);
  convf2b_kernel<<<1536, blk, 0, stream>>>(enc, enc_bf);
  bokeh_down_kernel<<<8, blk, 0, stream>>>(bok, kbd, vbd, tkv);
  bokeh_up_kernel<<<96, blk, 0, stream>>>(tkv, kbu, vbu, kdvd);

  convw_kernel<<<dim3(9216, 3), blk, 0, stream>>>(Wq, Wk, Wv, w3);
  gemm3_kernel<<<1152, blk, 0, stream>>>(hs_bf, w3, bq, bk, bv, q0, k0, v0, 2048);
  convw_kernel<<<dim3(9216, 3), blk, 0, stream>>>(Waq, Wak, Wav, w3);
  gemm3_kernel<<<288, blk, 0, stream>>>(enc_bf, w3, baq, bak, bav, eq, ek, ev, 512);

  lora_down2_kernel<<<dim3(2048, 2), blk, 0, stream>>>(q0, k0, qad, kad, tmpq, tmpk);

  pack_kernel<<<dim3(SEQ / 4, HEADS, 2), blk, 0, stream>>>(
      q0, k0, eq, ek, tmpq, tmpk, qau, kau, nq, nk, naq, nak, rc, rsn, Qp, Kp);
  vpackT_kernel<<<dim3(SEQ / 64, HEADS), blk, 0, stream>>>(v0, ev, Vtg);

  attn_kernel<<<dim3(SEQ / 64, HEADS), blk, 0, stream>>>(Qp, Kp, Vtg, kdvd, attnbf);

  convw_kernel<<<dim3(9216, 2), blk, 0, stream>>>(Wo, Wao, Wao, w3);
  gemm_out_kernel<<<480, blk, 0, stream>>>(attnbf, w3, bo, bao, out);
}